// Round 5
// baseline (47066.348 us; speedup 1.0000x reference)
//
#include <hip/hip_runtime.h>

#define B 128
#define T 1024

typedef unsigned short u16;
typedef unsigned int   u32;
typedef unsigned long long u64;

__device__ __forceinline__ float sigm(float x){ return 1.f/(1.f+__expf(-x)); }
__device__ __forceinline__ float tanh_(float x){ return 1.f - 2.f/(1.f+__expf(2.f*x)); }
__device__ __forceinline__ u16 f2b(float f){
  u32 u = __float_as_uint(f);
  u += 0x7FFFu + ((u>>16)&1u);
  return (u16)(u>>16);
}
__device__ __forceinline__ float bf(u16 s){ return __uint_as_float(((u32)s)<<16); }
__device__ __forceinline__ float blo(u32 q){ return __uint_as_float(q<<16); }
__device__ __forceinline__ float bhi(u32 q){ return __uint_as_float(q & 0xffff0000u); }

// ---- static device buffers ----
// exchange/history buffers as u64 words (4 bf16 each) so atomics are well-typed:
// g_h1T: [cl][t][k<304][half<2] ; half = 4 batch lanes (16B per (cl,t,k))
__device__ __align__(16) u64 g_h1T[(u32)16*T*304*2];
__device__ __align__(16) u64 g_h2T[(u32)16*T*256*2];
__device__ u16    g_xp3[(u32)B*T*256];      // w_ih3 @ h2, bf16
__device__ float4 g_xp4[(u32)B*T];          // w_ih4 @ h3, fp32
__device__ int    g_flag[2][16][16];        // per-layer, per-cluster, per-WG step flags

__global__ void k_zero_flags(){
  int i = threadIdx.x;
  if (i < 2*16*16) ((int*)g_flag)[i] = 0;
}

// ============== Layer 1: H=300. 16 clusters x 15 WGs x 320 thr. ==============
// thread=(rq 0..19, ks 0..15): rows 4rq..4rq+3, all 8 batch, k-slice ks (19 k, strided).
__global__ __launch_bounds__(320) void k_l1(const float* __restrict__ x,
    const float* __restrict__ wih, const float* __restrict__ whh,
    const float* __restrict__ bih, const float* __restrict__ bhh){
  __shared__ float sW[304*80];     // [k][col-quad c], quad c at k holds rq=(c-(k&15)) mod 20
  __shared__ uint4 sV[304];        // [k] = 8 batch bf16 packed
  __shared__ float sG[80*8];       // reduced gate pre-activations [row][b]
  __shared__ float sBsum[80], sWih[80];
  __shared__ float sX[8];
  const int tid = threadIdx.x;
  const int cl = blockIdx.x / 15, wg = blockIdx.x % 15;
  const int b0 = cl*8, u0 = wg*20;

  for (int idx = tid; idx < 304*20; idx += 320){
    int k = idx / 20, c = idx % 20;
    int rq = c + 20 - (k & 15); if (rq >= 20) rq -= 20;
    float4 w;
    #pragma unroll
    for (int j = 0; j < 4; ++j){
      int r = 4*rq + j;                  // 0..79, r = g*20+ul
      int g = r / 20, ul = r % 20;
      int grow = g*300 + u0 + ul;
      (&w.x)[j] = (k < 300) ? whh[grow*300 + k] : 0.f;
    }
    *(float4*)&sW[k*80 + 4*c] = w;
  }
  for (int idx = tid; idx < 80; idx += 320){
    int g = idx / 20, ul = idx % 20;
    int grow = g*300 + u0 + ul;
    sBsum[idx] = bih[grow] + bhh[grow];
    sWih[idx]  = wih[grow];
  }
  if (tid < 304) sV[tid] = make_uint4(0,0,0,0);
  __syncthreads();

  const int rq = tid >> 4, ks = tid & 15;
  int cq = rq + ks; if (cq >= 20) cq -= 20;
  float c_state = 0.f;
  int* myflag = &g_flag[0][cl][0];

  for (int t = 0; t < T; ++t){
    float xv = 0.f;
    if (tid < 8) xv = x[(b0+tid)*T + t];
    float acc[4][8];
    #pragma unroll
    for (int j=0;j<4;++j){
      #pragma unroll
      for (int b=0;b<8;++b) acc[j][b] = 0.f;
    }
    #pragma unroll 4
    for (int kk = 0; kk < 19; ++kk){
      int k = kk*16 + ks;
      float4 w = *(const float4*)&sW[k*80 + 4*cq];
      uint4 q = sV[k];
      float v[8] = { blo(q.x), bhi(q.x), blo(q.y), bhi(q.y),
                     blo(q.z), bhi(q.z), blo(q.w), bhi(q.w) };
      #pragma unroll
      for (int j=0;j<4;++j){
        float wj = (&w.x)[j];
        #pragma unroll
        for (int b=0;b<8;++b) acc[j][b] = __builtin_fmaf(wj, v[b], acc[j][b]);
      }
    }
    // k-reduce across the 16 ks-lanes (same wave)
    #pragma unroll
    for (int m = 1; m < 16; m <<= 1){
      #pragma unroll
      for (int j=0;j<4;++j){
        #pragma unroll
        for (int b=0;b<8;++b) acc[j][b] += __shfl_xor(acc[j][b], m);
      }
    }
    if (ks < 8){
      int j = ks >> 1, h = ks & 1;
      *(float4*)&sG[(4*rq + j)*8 + 4*h] =
        make_float4(acc[j][4*h+0], acc[j][4*h+1], acc[j][4*h+2], acc[j][4*h+3]);
    }
    if (tid < 8) sX[tid] = xv;
    __syncthreads();
    if (tid < 160){
      int u = tid >> 3, b = tid & 7;
      float gs[4];
      #pragma unroll
      for (int g=0; g<4; ++g){
        int r = g*20 + u;
        gs[g] = sBsum[r] + sX[b]*sWih[r] + sG[r*8 + b];
      }
      float cg = sigm(gs[1])*c_state + sigm(gs[0])*tanh_(gs[2]);
      c_state = cg;
      float h = sigm(gs[3])*tanh_(cg);
      u32 us = f2b(h);
      u32 other = (u32)__shfl_xor((int)us, 1);
      if (!(b & 1)){
        u32 pk = us | (other << 16);
        u32 widx = ((u32)(cl*T + t)*304 + (u32)(u0 + u))*4 + (u32)(b >> 1);
        __hip_atomic_store((u32*)g_h1T + widx, pk, __ATOMIC_RELAXED, __HIP_MEMORY_SCOPE_AGENT);
      }
    }
    __syncthreads();  // drains stores of all waves before flag
    if (tid == 0)
      __hip_atomic_store(&myflag[wg], t+1, __ATOMIC_RELEASE, __HIP_MEMORY_SCOPE_AGENT);
    if (t+1 < T){
      if (tid < 300){
        int* fp = &myflag[tid / 20];
        while (__hip_atomic_load(fp, __ATOMIC_ACQUIRE, __HIP_MEMORY_SCOPE_AGENT) <= t) {}
        u32 base = ((u32)(cl*T + t)*304 + (u32)tid)*2;
        u64 lo = __hip_atomic_load(&g_h1T[base],   __ATOMIC_RELAXED, __HIP_MEMORY_SCOPE_AGENT);
        u64 hi = __hip_atomic_load(&g_h1T[base+1], __ATOMIC_RELAXED, __HIP_MEMORY_SCOPE_AGENT);
        sV[tid] = make_uint4((u32)lo, (u32)(lo>>32), (u32)hi, (u32)(hi>>32));
      }
      __syncthreads();
    }
  }
}

// ============== Layer 2: H=256, wih2 fused (staged+computed BEFORE the spin). ==============
// 16 clusters x 16 WGs x 256 thr; thread=(rq 0..15, ks 0..15).
__global__ __launch_bounds__(256) void k_l2(
    const float* __restrict__ wih, const float* __restrict__ whh,
    const float* __restrict__ bih, const float* __restrict__ bhh){
  __shared__ float sWr[256*64];    // fp32, col-quad c = rq ^ (k&15)
  __shared__ u16   sWx[304*72];    // bf16, same swizzle, stride 72
  __shared__ uint4 sVh[256];
  __shared__ uint4 sVx[2][304];
  __shared__ float sG[64*8];
  __shared__ float sBsum[64];
  const int tid = threadIdx.x;
  const int cl = blockIdx.x >> 4, wg = blockIdx.x & 15;
  const int u0 = wg*16;

  for (int idx = tid; idx < 256*16; idx += 256){
    int k = idx >> 4, c = idx & 15;
    int rqs = c ^ (k & 15);
    float4 w;
    #pragma unroll
    for (int j=0;j<4;++j){
      int r = 4*rqs + j; int g = r >> 4, ul = r & 15;
      (&w.x)[j] = whh[(g*256 + u0 + ul)*256 + k];
    }
    *(float4*)&sWr[k*64 + 4*c] = w;
  }
  for (int idx = tid; idx < 304*16; idx += 256){
    int k = idx >> 4, c = idx & 15;
    int rqs = c ^ (k & 15);
    ushort4 w;
    #pragma unroll
    for (int j=0;j<4;++j){
      int r = 4*rqs + j; int g = r >> 4, ul = r & 15;
      float wv = (k < 300) ? wih[(g*256 + u0 + ul)*300 + k] : 0.f;
      (&w.x)[j] = f2b(wv);
    }
    *(ushort4*)&sWx[k*72 + 4*c] = w;
  }
  for (int idx = tid; idx < 64; idx += 256){
    int g = idx >> 4, ul = idx & 15;
    int grow = g*256 + u0 + ul;
    sBsum[idx] = bih[grow] + bhh[grow];
  }
  sVh[tid] = make_uint4(0,0,0,0);
  for (int kx = tid; kx < 304; kx += 256)
    sVx[0][kx] = *(const uint4*)&g_h1T[((u32)(cl*T + 0)*304 + (u32)kx)*2];
  __syncthreads();

  const int rq = tid >> 4, ks = tid & 15;
  const int cq = rq ^ ks;
  float c_state = 0.f;
  int* myflag = &g_flag[1][cl][0];
  int cur = 0;

  for (int t = 0; t < T; ++t){
    uint4 pf0 = make_uint4(0,0,0,0), pf1 = pf0;
    if (t+1 < T && tid < 152){
      u32 base = ((u32)(cl*T + (t+1))*304)*2;
      pf0 = *(const uint4*)&g_h1T[base + (u32)tid*2];
      pf1 = *(const uint4*)&g_h1T[base + (u32)(tid+152)*2];
    }
    float acc[4][8];
    #pragma unroll
    for (int j=0;j<4;++j){
      #pragma unroll
      for (int b=0;b<8;++b) acc[j][b] = 0.f;
    }
    // input part (h1[t], no dependence on exchange)
    #pragma unroll 4
    for (int kk = 0; kk < 19; ++kk){
      int k = kk*16 + ks;
      ushort4 wu = *(const ushort4*)&sWx[k*72 + 4*cq];
      uint4 q = sVx[cur][k];
      float v[8] = { blo(q.x), bhi(q.x), blo(q.y), bhi(q.y),
                     blo(q.z), bhi(q.z), blo(q.w), bhi(q.w) };
      #pragma unroll
      for (int j=0;j<4;++j){
        float wj = bf((&wu.x)[j]);
        #pragma unroll
        for (int b=0;b<8;++b) acc[j][b] = __builtin_fmaf(wj, v[b], acc[j][b]);
      }
    }
    // recurrent part (h2[t-1])
    #pragma unroll 4
    for (int kk = 0; kk < 16; ++kk){
      int k = kk*16 + ks;
      float4 w = *(const float4*)&sWr[k*64 + 4*cq];
      uint4 q = sVh[k];
      float v[8] = { blo(q.x), bhi(q.x), blo(q.y), bhi(q.y),
                     blo(q.z), bhi(q.z), blo(q.w), bhi(q.w) };
      #pragma unroll
      for (int j=0;j<4;++j){
        float wj = (&w.x)[j];
        #pragma unroll
        for (int b=0;b<8;++b) acc[j][b] = __builtin_fmaf(wj, v[b], acc[j][b]);
      }
    }
    #pragma unroll
    for (int m = 1; m < 16; m <<= 1){
      #pragma unroll
      for (int j=0;j<4;++j){
        #pragma unroll
        for (int b=0;b<8;++b) acc[j][b] += __shfl_xor(acc[j][b], m);
      }
    }
    if (ks < 8){
      int j = ks >> 1, h = ks & 1;
      *(float4*)&sG[(4*rq + j)*8 + 4*h] =
        make_float4(acc[j][4*h+0], acc[j][4*h+1], acc[j][4*h+2], acc[j][4*h+3]);
    }
    __syncthreads();
    if (tid < 128){
      int u = tid >> 3, b = tid & 7;
      float gs[4];
      #pragma unroll
      for (int g=0; g<4; ++g){
        int r = g*16 + u;
        gs[g] = sBsum[r] + sG[r*8 + b];
      }
      float cg = sigm(gs[1])*c_state + sigm(gs[0])*tanh_(gs[2]);
      c_state = cg;
      float h = sigm(gs[3])*tanh_(cg);
      u32 us = f2b(h);
      u32 other = (u32)__shfl_xor((int)us, 1);
      if (!(b & 1)){
        u32 pk = us | (other << 16);
        u32 widx = ((u32)(cl*T + t)*256 + (u32)(u0 + u))*4 + (u32)(b >> 1);
        __hip_atomic_store((u32*)g_h2T + widx, pk, __ATOMIC_RELAXED, __HIP_MEMORY_SCOPE_AGENT);
      }
    }
    __syncthreads();
    if (tid == 0)
      __hip_atomic_store(&myflag[wg], t+1, __ATOMIC_RELEASE, __HIP_MEMORY_SCOPE_AGENT);
    if (t+1 < T){
      if (tid < 152){ sVx[cur^1][tid] = pf0; sVx[cur^1][tid+152] = pf1; }
      {
        int* fp = &myflag[tid >> 4];
        while (__hip_atomic_load(fp, __ATOMIC_ACQUIRE, __HIP_MEMORY_SCOPE_AGENT) <= t) {}
        u32 base = ((u32)(cl*T + t)*256 + (u32)tid)*2;
        u64 lo = __hip_atomic_load(&g_h2T[base],   __ATOMIC_RELAXED, __HIP_MEMORY_SCOPE_AGENT);
        u64 hi = __hip_atomic_load(&g_h2T[base+1], __ATOMIC_RELAXED, __HIP_MEMORY_SCOPE_AGENT);
        sVh[tid] = make_uint4((u32)lo, (u32)(lo>>32), (u32)hi, (u32)(hi>>32));
      }
      __syncthreads();
      cur ^= 1;
    }
  }
}

// ============== G3: xp3[B*T,256] = h2 @ wih3^T (tiled, off the serial path) ==============
__global__ __launch_bounds__(256) void k_g3(const float* __restrict__ wih3){
  __shared__ u16 At[256*72];   // [k][local row], stride 72
  __shared__ u16 Bt[256*72];   // [k][local col]
  const int tid = threadIdx.x;
  const int nt = blockIdx.x & 3, mt = blockIdx.x >> 2;
  const int cl = mt >> 7, t0 = (mt & 127)*8, n0 = nt*64;
  {
    int i = tid >> 5, kb = tid & 31;
    for (int kk = 0; kk < 8; ++kk){
      int k = kk*32 + kb;
      uint4 q = *(const uint4*)&g_h2T[((u32)(cl*T + t0 + i)*256 + (u32)k)*2];
      *(uint4*)&At[k*72 + i*8] = q;   // local row = i*8 + b
    }
  }
  {
    int nl = tid & 63, kq4 = tid >> 6;
    for (int kk = 0; kk < 16; ++kk){
      int kq = kq4*16 + kk;
      float4 w = *(const float4*)&wih3[(n0+nl)*256 + 4*kq];
      #pragma unroll
      for (int m=0;m<4;++m) Bt[(4*kq+m)*72 + nl] = f2b((&w.x)[m]);
    }
  }
  __syncthreads();
  const int r4 = tid >> 4, c4 = tid & 15;
  float acc[4][4];
  #pragma unroll
  for (int j=0;j<4;++j){
    #pragma unroll
    for (int m=0;m<4;++m) acc[j][m] = 0.f;
  }
  #pragma unroll 4
  for (int k = 0; k < 256; ++k){
    ushort4 a = *(const ushort4*)&At[k*72 + 4*r4];
    ushort4 b = *(const ushort4*)&Bt[k*72 + 4*c4];
    float av[4] = { bf(a.x), bf(a.y), bf(a.z), bf(a.w) };
    float bv[4] = { bf(b.x), bf(b.y), bf(b.z), bf(b.w) };
    #pragma unroll
    for (int j=0;j<4;++j){
      #pragma unroll
      for (int m=0;m<4;++m) acc[j][m] = __builtin_fmaf(av[j], bv[m], acc[j][m]);
    }
  }
  #pragma unroll
  for (int j=0;j<4;++j){
    int l = 4*r4 + j;
    int tt = t0 + (l >> 3), bg = cl*8 + (l & 7);
    ushort4 o;
    #pragma unroll
    for (int m=0;m<4;++m) (&o.x)[m] = f2b(acc[j][m]);
    *(ushort4*)&g_xp3[((u32)bg*T + (u32)tt)*256 + (u32)(n0 + 4*c4)] = o;
  }
}

// ============== Layer 3 (+xp4): one wave per batch element, wave-synchronous ==============
__global__ __launch_bounds__(64) void k_l3(
    const float* __restrict__ whh, const float* __restrict__ bih,
    const float* __restrict__ bhh, const float* __restrict__ wih4){
  __shared__ float sW[64*256];   // [k][row], row-quad at 4*lane
  __shared__ float sV[64];
  __shared__ float sG[256];
  __shared__ float sBs[256];
  const int lane = threadIdx.x;
  const int b = blockIdx.x;
  #pragma unroll 1
  for (int j = 0; j < 4; ++j){
    int r = 4*lane + j;
    for (int kq = 0; kq < 16; ++kq){
      float4 w = *(const float4*)&whh[r*64 + 4*kq];
      #pragma unroll
      for (int m=0;m<4;++m) sW[(4*kq+m)*256 + r] = (&w.x)[m];
    }
  }
  for (int idx = lane; idx < 256; idx += 64) sBs[idx] = bih[idx] + bhh[idx];
  float w4g[4];
  #pragma unroll
  for (int g=0;g<4;++g) w4g[g] = wih4[g*64 + lane];
  sV[lane] = 0.f;
  float c_state = 0.f;
  __syncthreads();

  for (int t = 0; t < T; ++t){
    u16 xr[4];
    #pragma unroll
    for (int g=0;g<4;++g) xr[g] = g_xp3[((u32)b*T + (u32)t)*256 + (u32)(g*64 + lane)];
    float a0=0.f, a1=0.f, a2=0.f, a3=0.f;
    #pragma unroll 4
    for (int k4 = 0; k4 < 16; ++k4){
      float4 v4 = *(const float4*)&sV[4*k4];
      #pragma unroll
      for (int m=0;m<4;++m){
        float4 w = *(const float4*)&sW[(4*k4+m)*256 + 4*lane];
        float vm = (&v4.x)[m];
        a0 = __builtin_fmaf(w.x, vm, a0);
        a1 = __builtin_fmaf(w.y, vm, a1);
        a2 = __builtin_fmaf(w.z, vm, a2);
        a3 = __builtin_fmaf(w.w, vm, a3);
      }
    }
    *(float4*)&sG[4*lane] = make_float4(a0,a1,a2,a3);
    __syncthreads();
    float gs[4];
    #pragma unroll
    for (int g=0;g<4;++g) gs[g] = sBs[g*64 + lane] + bf(xr[g]) + sG[g*64 + lane];
    float cg = sigm(gs[1])*c_state + sigm(gs[0])*tanh_(gs[2]);
    c_state = cg;
    float h = sigm(gs[3])*tanh_(cg);
    sV[lane] = h;
    float p[4];
    #pragma unroll
    for (int g=0;g<4;++g) p[g] = w4g[g]*h;
    #pragma unroll
    for (int off = 32; off; off >>= 1){
      #pragma unroll
      for (int g=0;g<4;++g) p[g] += __shfl_down(p[g], off);
    }
    if (lane == 0) g_xp4[(u32)b*T + t] = make_float4(p[0],p[1],p[2],p[3]);
    __syncthreads();
  }
}

// ============== Layer 4: H=1 scalar scan ==============
__global__ void k_l4(const float* __restrict__ whh, const float* __restrict__ bih,
                     const float* __restrict__ bhh, float* __restrict__ out){
  int b = blockIdx.x*64 + threadIdx.x;
  float wi=whh[0], wf=whh[1], wg=whh[2], wo=whh[3];
  float bi=bih[0]+bhh[0], bf_=bih[1]+bhh[1], bg=bih[2]+bhh[2], bo=bih[3]+bhh[3];
  float h=0.f, c=0.f;
  const float4* xp = &g_xp4[(u32)b*T];
  float4 nxt = xp[0];
  for (int t=0; t<T; ++t){
    float4 cur = nxt;
    if (t+1 < T) nxt = xp[t+1];
    float ig = sigm(cur.x + wi*h + bi);
    float fg = sigm(cur.y + wf*h + bf_);
    float gg = tanh_(cur.z + wg*h + bg);
    float og = sigm(cur.w + wo*h + bo);
    c = fg*c + ig*gg;
    h = og*tanh_(c);
  }
  out[b] = h;
}

extern "C" void kernel_launch(void* const* d_in, const int* in_sizes, int n_in,
                              void* d_out, int out_size, void* d_ws, size_t ws_size,
                              hipStream_t stream){
  (void)in_sizes; (void)n_in; (void)d_ws; (void)ws_size; (void)out_size;
  const float* x    = (const float*)d_in[0];
  const float* wih1 = (const float*)d_in[1];
  const float* whh1 = (const float*)d_in[2];
  const float* bih1 = (const float*)d_in[3];
  const float* bhh1 = (const float*)d_in[4];
  const float* wih2 = (const float*)d_in[5];
  const float* whh2 = (const float*)d_in[6];
  const float* bih2 = (const float*)d_in[7];
  const float* bhh2 = (const float*)d_in[8];
  const float* wih3 = (const float*)d_in[9];
  const float* whh3 = (const float*)d_in[10];
  const float* bih3 = (const float*)d_in[11];
  const float* bhh3 = (const float*)d_in[12];
  const float* wih4 = (const float*)d_in[13];
  const float* whh4 = (const float*)d_in[14];
  const float* bih4 = (const float*)d_in[15];
  const float* bhh4 = (const float*)d_in[16];

  hipLaunchKernelGGL(k_zero_flags, dim3(1), dim3(512), 0, stream);
  hipLaunchKernelGGL(k_l1, dim3(240), dim3(320), 0, stream, x, wih1, whh1, bih1, bhh1);
  hipLaunchKernelGGL(k_l2, dim3(256), dim3(256), 0, stream, wih2, whh2, bih2, bhh2);
  hipLaunchKernelGGL(k_g3, dim3(8192), dim3(256), 0, stream, wih3);
  hipLaunchKernelGGL(k_l3, dim3(128), dim3(64), 0, stream, whh3, bih3, bhh3, wih4);
  hipLaunchKernelGGL(k_l4, dim3(2), dim3(64), 0, stream, whh4, bih4, bhh4, (float*)d_out);
}

// Round 6
// 13568.192 us; speedup vs baseline: 3.4689x; 3.4689x over previous
//
#include <hip/hip_runtime.h>

#define B 128
#define T 1024

typedef unsigned short u16;
typedef unsigned int   u32;
typedef unsigned long long u64;

__device__ __forceinline__ float sigm(float x){ return 1.f/(1.f+__expf(-x)); }
__device__ __forceinline__ float tanh_(float x){ return 1.f - 2.f/(1.f+__expf(2.f*x)); }
__device__ __forceinline__ u16 f2b(float f){
  u32 u = __float_as_uint(f);
  u += 0x7FFFu + ((u>>16)&1u);
  return (u16)(u>>16);
}
__device__ __forceinline__ float bf(u16 s){ return __uint_as_float(((u32)s)<<16); }
__device__ __forceinline__ float blo(u32 q){ return __uint_as_float(q<<16); }
__device__ __forceinline__ float bhi(u32 q){ return __uint_as_float(q & 0xffff0000u); }

// ---- static device buffers ----
// exchange/history as u64 words (4 bf16 each): g_h1T [cl][t][k<304][half<2]
__device__ __align__(16) u64 g_h1T[(u32)16*T*304*2];
__device__ __align__(16) u64 g_h2T[(u32)16*T*256*2];
__device__ u16    g_xp3[(u32)B*T*256];      // w_ih3 @ h2, bf16
__device__ float4 g_xp4[(u32)B*T];          // w_ih4 @ h3, fp32
__device__ int    g_cnt[2][16][32];         // per-layer, per-cluster step counter (128B strided)

__global__ void k_zero_flags(){
  int i = threadIdx.x;
  if (i < 2*16*32) ((int*)g_cnt)[i] = 0;
}

// ============== Layer 1: H=300. 16 clusters x 15 WGs x 320 thr. ==============
// thread=(rq 0..19, ks 0..15): rows 4rq..4rq+3, all 8 batch, k-slice ks (19 k, strided).
__global__ __launch_bounds__(320) void k_l1(const float* __restrict__ x,
    const float* __restrict__ wih, const float* __restrict__ whh,
    const float* __restrict__ bih, const float* __restrict__ bhh){
  __shared__ float sW[304*84];     // stride 84 floats: bank = (20k+4c)%32 -> ~2-way
  __shared__ uint4 sV[304];        // [k] = 8 batch bf16 packed
  __shared__ float sG[80*8];       // reduced gate pre-activations [row][b]
  __shared__ float sBsum[80], sWih[80];
  __shared__ float sXall[8*1024];  // x staged: [t][b]
  const int tid = threadIdx.x;
  const int cl = blockIdx.x / 15, wg = blockIdx.x % 15;
  const int b0 = cl*8, u0 = wg*20;

  for (int idx = tid; idx < 304*20; idx += 320){
    int k = idx / 20, c = idx % 20;
    int rq = c + 20 - (k & 15); if (rq >= 20) rq -= 20;
    float4 w;
    #pragma unroll
    for (int j = 0; j < 4; ++j){
      int r = 4*rq + j;                  // 0..79, r = g*20+ul
      int g = r / 20, ul = r % 20;
      int grow = g*300 + u0 + ul;
      (&w.x)[j] = (k < 300) ? whh[grow*300 + k] : 0.f;
    }
    *(float4*)&sW[k*84 + 4*c] = w;
  }
  for (int idx = tid; idx < 80; idx += 320){
    int g = idx / 20, ul = idx % 20;
    int grow = g*300 + u0 + ul;
    sBsum[idx] = bih[grow] + bhh[grow];
    sWih[idx]  = wih[grow];
  }
  for (int idx = tid; idx < 8*1024; idx += 320){
    int b = idx >> 10, t = idx & 1023;
    sXall[t*8 + b] = x[(b0+b)*1024 + t];
  }
  if (tid < 304) sV[tid] = make_uint4(0,0,0,0);
  __syncthreads();

  const int rq = tid >> 4, ks = tid & 15;
  int cq = rq + ks; if (cq >= 20) cq -= 20;
  float c_state = 0.f;
  int* cnt = &g_cnt[0][cl][0];

  for (int t = 0; t < T; ++t){
    float acc[4][8];
    #pragma unroll
    for (int j=0;j<4;++j){
      #pragma unroll
      for (int b=0;b<8;++b) acc[j][b] = 0.f;
    }
    #pragma unroll 4
    for (int kk = 0; kk < 19; ++kk){
      int k = kk*16 + ks;
      float4 w = *(const float4*)&sW[k*84 + 4*cq];
      uint4 q = sV[k];
      float v[8] = { blo(q.x), bhi(q.x), blo(q.y), bhi(q.y),
                     blo(q.z), bhi(q.z), blo(q.w), bhi(q.w) };
      #pragma unroll
      for (int j=0;j<4;++j){
        float wj = (&w.x)[j];
        #pragma unroll
        for (int b=0;b<8;++b) acc[j][b] = __builtin_fmaf(wj, v[b], acc[j][b]);
      }
    }
    // k-reduce across the 16 ks-lanes (same wave)
    #pragma unroll
    for (int m = 1; m < 16; m <<= 1){
      #pragma unroll
      for (int j=0;j<4;++j){
        #pragma unroll
        for (int b=0;b<8;++b) acc[j][b] += __shfl_xor(acc[j][b], m);
      }
    }
    if (ks < 8){
      int j = ks >> 1, h = ks & 1;
      *(float4*)&sG[(4*rq + j)*8 + 4*h] =
        make_float4(acc[j][4*h+0], acc[j][4*h+1], acc[j][4*h+2], acc[j][4*h+3]);
    }
    __syncthreads();
    if (tid < 160){
      int u = tid >> 3, b = tid & 7;
      float gs[4];
      #pragma unroll
      for (int g=0; g<4; ++g){
        int r = g*20 + u;
        gs[g] = sBsum[r] + sXall[t*8+b]*sWih[r] + sG[r*8 + b];
      }
      float cg = sigm(gs[1])*c_state + sigm(gs[0])*tanh_(gs[2]);
      c_state = cg;
      float h = sigm(gs[3])*tanh_(cg);
      u32 us = f2b(h);
      u32 other = (u32)__shfl_xor((int)us, 1);
      if (!(b & 1)){
        u32 pk = us | (other << 16);
        u32 widx = ((u32)(cl*T + t)*304 + (u32)(u0 + u))*4 + (u32)(b >> 1);
        __hip_atomic_store((u32*)g_h1T + widx, pk, __ATOMIC_RELAXED, __HIP_MEMORY_SCOPE_AGENT);
      }
    }
    __syncthreads();  // drains vmcnt: all h-stores complete (at L3) before counter bump
    if (tid == 0)
      __hip_atomic_fetch_add(cnt, 1, __ATOMIC_RELAXED, __HIP_MEMORY_SCOPE_AGENT);
    if (t+1 < T){
      if (tid == 0){
        while (__hip_atomic_load(cnt, __ATOMIC_RELAXED, __HIP_MEMORY_SCOPE_AGENT) < (t+1)*15) {}
      }
      __syncthreads();   // all threads wait until poller saw the full step
      if (tid < 300){
        u32 base = ((u32)(cl*T + t)*304 + (u32)tid)*2;
        u64 lo = __hip_atomic_load(&g_h1T[base],   __ATOMIC_RELAXED, __HIP_MEMORY_SCOPE_AGENT);
        u64 hi = __hip_atomic_load(&g_h1T[base+1], __ATOMIC_RELAXED, __HIP_MEMORY_SCOPE_AGENT);
        sV[tid] = make_uint4((u32)lo, (u32)(lo>>32), (u32)hi, (u32)(hi>>32));
      }
      __syncthreads();
    }
  }
}

// ============== Layer 2: H=256, wih2 fused. 16 clusters x 16 WGs x 256 thr. ==============
__global__ __launch_bounds__(256) void k_l2(
    const float* __restrict__ wih, const float* __restrict__ whh,
    const float* __restrict__ bih, const float* __restrict__ bhh){
  __shared__ float sWr[256*72];    // stride 72 floats: bank = (8k+4c)%32 -> ~2-way
  __shared__ u16   sWx[304*72];    // bf16, stride 72 shorts
  __shared__ uint4 sVh[256];
  __shared__ uint4 sVx[2][304];
  __shared__ float sG[64*8];
  __shared__ float sBsum[64];
  const int tid = threadIdx.x;
  const int cl = blockIdx.x >> 4, wg = blockIdx.x & 15;
  const int u0 = wg*16;

  for (int idx = tid; idx < 256*16; idx += 256){
    int k = idx >> 4, c = idx & 15;
    int rqs = c ^ (k & 15);
    float4 w;
    #pragma unroll
    for (int j=0;j<4;++j){
      int r = 4*rqs + j; int g = r >> 4, ul = r & 15;
      (&w.x)[j] = whh[(g*256 + u0 + ul)*256 + k];
    }
    *(float4*)&sWr[k*72 + 4*c] = w;
  }
  for (int idx = tid; idx < 304*16; idx += 256){
    int k = idx >> 4, c = idx & 15;
    int rqs = c ^ (k & 15);
    ushort4 w;
    #pragma unroll
    for (int j=0;j<4;++j){
      int r = 4*rqs + j; int g = r >> 4, ul = r & 15;
      float wv = (k < 300) ? wih[(g*256 + u0 + ul)*300 + k] : 0.f;
      (&w.x)[j] = f2b(wv);
    }
    *(ushort4*)&sWx[k*72 + 4*c] = w;
  }
  for (int idx = tid; idx < 64; idx += 256){
    int g = idx >> 4, ul = idx & 15;
    int grow = g*256 + u0 + ul;
    sBsum[idx] = bih[grow] + bhh[grow];
  }
  sVh[tid] = make_uint4(0,0,0,0);
  for (int kx = tid; kx < 304; kx += 256)
    sVx[0][kx] = *(const uint4*)&g_h1T[((u32)(cl*T + 0)*304 + (u32)kx)*2];
  __syncthreads();

  const int rq = tid >> 4, ks = tid & 15;
  const int cq = rq ^ ks;
  float c_state = 0.f;
  int* cnt = &g_cnt[1][cl][0];
  int cur = 0;

  for (int t = 0; t < T; ++t){
    uint4 pf0 = make_uint4(0,0,0,0), pf1 = pf0;
    if (t+1 < T && tid < 152){
      u32 base = ((u32)(cl*T + (t+1))*304)*2;
      pf0 = *(const uint4*)&g_h1T[base + (u32)tid*2];
      pf1 = *(const uint4*)&g_h1T[base + (u32)(tid+152)*2];
    }
    float acc[4][8];
    #pragma unroll
    for (int j=0;j<4;++j){
      #pragma unroll
      for (int b=0;b<8;++b) acc[j][b] = 0.f;
    }
    // input part (h1[t], no dependence on exchange)
    #pragma unroll 4
    for (int kk = 0; kk < 19; ++kk){
      int k = kk*16 + ks;
      ushort4 wu = *(const ushort4*)&sWx[k*72 + 4*cq];
      uint4 q = sVx[cur][k];
      float v[8] = { blo(q.x), bhi(q.x), blo(q.y), bhi(q.y),
                     blo(q.z), bhi(q.z), blo(q.w), bhi(q.w) };
      #pragma unroll
      for (int j=0;j<4;++j){
        float wj = bf((&wu.x)[j]);
        #pragma unroll
        for (int b=0;b<8;++b) acc[j][b] = __builtin_fmaf(wj, v[b], acc[j][b]);
      }
    }
    // recurrent part (h2[t-1])
    #pragma unroll 4
    for (int kk = 0; kk < 16; ++kk){
      int k = kk*16 + ks;
      float4 w = *(const float4*)&sWr[k*72 + 4*cq];
      uint4 q = sVh[k];
      float v[8] = { blo(q.x), bhi(q.x), blo(q.y), bhi(q.y),
                     blo(q.z), bhi(q.z), blo(q.w), bhi(q.w) };
      #pragma unroll
      for (int j=0;j<4;++j){
        float wj = (&w.x)[j];
        #pragma unroll
        for (int b=0;b<8;++b) acc[j][b] = __builtin_fmaf(wj, v[b], acc[j][b]);
      }
    }
    #pragma unroll
    for (int m = 1; m < 16; m <<= 1){
      #pragma unroll
      for (int j=0;j<4;++j){
        #pragma unroll
        for (int b=0;b<8;++b) acc[j][b] += __shfl_xor(acc[j][b], m);
      }
    }
    if (ks < 8){
      int j = ks >> 1, h = ks & 1;
      *(float4*)&sG[(4*rq + j)*8 + 4*h] =
        make_float4(acc[j][4*h+0], acc[j][4*h+1], acc[j][4*h+2], acc[j][4*h+3]);
    }
    __syncthreads();
    if (tid < 128){
      int u = tid >> 3, b = tid & 7;
      float gs[4];
      #pragma unroll
      for (int g=0; g<4; ++g){
        int r = g*16 + u;
        gs[g] = sBsum[r] + sG[r*8 + b];
      }
      float cg = sigm(gs[1])*c_state + sigm(gs[0])*tanh_(gs[2]);
      c_state = cg;
      float h = sigm(gs[3])*tanh_(cg);
      u32 us = f2b(h);
      u32 other = (u32)__shfl_xor((int)us, 1);
      if (!(b & 1)){
        u32 pk = us | (other << 16);
        u32 widx = ((u32)(cl*T + t)*256 + (u32)(u0 + u))*4 + (u32)(b >> 1);
        __hip_atomic_store((u32*)g_h2T + widx, pk, __ATOMIC_RELAXED, __HIP_MEMORY_SCOPE_AGENT);
      }
    }
    __syncthreads();  // drains vmcnt: h2-stores complete before counter bump
    if (tid == 0)
      __hip_atomic_fetch_add(cnt, 1, __ATOMIC_RELAXED, __HIP_MEMORY_SCOPE_AGENT);
    if (t+1 < T){
      if (tid < 152){ sVx[cur^1][tid] = pf0; sVx[cur^1][tid+152] = pf1; }
      if (tid == 0){
        while (__hip_atomic_load(cnt, __ATOMIC_RELAXED, __HIP_MEMORY_SCOPE_AGENT) < (t+1)*16) {}
      }
      __syncthreads();
      {
        u32 base = ((u32)(cl*T + t)*256 + (u32)tid)*2;
        u64 lo = __hip_atomic_load(&g_h2T[base],   __ATOMIC_RELAXED, __HIP_MEMORY_SCOPE_AGENT);
        u64 hi = __hip_atomic_load(&g_h2T[base+1], __ATOMIC_RELAXED, __HIP_MEMORY_SCOPE_AGENT);
        sVh[tid] = make_uint4((u32)lo, (u32)(lo>>32), (u32)hi, (u32)(hi>>32));
      }
      __syncthreads();
      cur ^= 1;
    }
  }
}

// ============== G3: xp3[B*T,256] = h2 @ wih3^T (tiled, off the serial path) ==============
__global__ __launch_bounds__(256) void k_g3(const float* __restrict__ wih3){
  __shared__ u16 At[256*72];   // [k][local row], stride 72
  __shared__ u16 Bt[256*72];   // [k][local col]
  const int tid = threadIdx.x;
  const int nt = blockIdx.x & 3, mt = blockIdx.x >> 2;
  const int cl = mt >> 7, t0 = (mt & 127)*8, n0 = nt*64;
  {
    int i = tid >> 5, kb = tid & 31;
    for (int kk = 0; kk < 8; ++kk){
      int k = kk*32 + kb;
      uint4 q = *(const uint4*)&g_h2T[((u32)(cl*T + t0 + i)*256 + (u32)k)*2];
      *(uint4*)&At[k*72 + i*8] = q;   // local row = i*8 + b
    }
  }
  {
    int nl = tid & 63, kq4 = tid >> 6;
    for (int kk = 0; kk < 16; ++kk){
      int kq = kq4*16 + kk;
      float4 w = *(const float4*)&wih3[(n0+nl)*256 + 4*kq];
      #pragma unroll
      for (int m=0;m<4;++m) Bt[(4*kq+m)*72 + nl] = f2b((&w.x)[m]);
    }
  }
  __syncthreads();
  const int r4 = tid >> 4, c4 = tid & 15;
  float acc[4][4];
  #pragma unroll
  for (int j=0;j<4;++j){
    #pragma unroll
    for (int m=0;m<4;++m) acc[j][m] = 0.f;
  }
  #pragma unroll 4
  for (int k = 0; k < 256; ++k){
    ushort4 a = *(const ushort4*)&At[k*72 + 4*r4];
    ushort4 b = *(const ushort4*)&Bt[k*72 + 4*c4];
    float av[4] = { bf(a.x), bf(a.y), bf(a.z), bf(a.w) };
    float bv[4] = { bf(b.x), bf(b.y), bf(b.z), bf(b.w) };
    #pragma unroll
    for (int j=0;j<4;++j){
      #pragma unroll
      for (int m=0;m<4;++m) acc[j][m] = __builtin_fmaf(av[j], bv[m], acc[j][m]);
    }
  }
  #pragma unroll
  for (int j=0;j<4;++j){
    int l = 4*r4 + j;
    int tt = t0 + (l >> 3), bg = cl*8 + (l & 7);
    ushort4 o;
    #pragma unroll
    for (int m=0;m<4;++m) (&o.x)[m] = f2b(acc[j][m]);
    *(ushort4*)&g_xp3[((u32)bg*T + (u32)tt)*256 + (u32)(n0 + 4*c4)] = o;
  }
}

// ============== Layer 3 (+xp4): one wave per batch element, wave-synchronous ==============
__global__ __launch_bounds__(64) void k_l3(
    const float* __restrict__ whh, const float* __restrict__ bih,
    const float* __restrict__ bhh, const float* __restrict__ wih4){
  __shared__ float sW[64*256];   // [k][row], row-quad at 4*lane
  __shared__ float sV[64];
  __shared__ float sG[256];
  __shared__ float sBs[256];
  const int lane = threadIdx.x;
  const int b = blockIdx.x;
  #pragma unroll 1
  for (int j = 0; j < 4; ++j){
    int r = 4*lane + j;
    for (int kq = 0; kq < 16; ++kq){
      float4 w = *(const float4*)&whh[r*64 + 4*kq];
      #pragma unroll
      for (int m=0;m<4;++m) sW[(4*kq+m)*256 + r] = (&w.x)[m];
    }
  }
  for (int idx = lane; idx < 256; idx += 64) sBs[idx] = bih[idx] + bhh[idx];
  float w4g[4];
  #pragma unroll
  for (int g=0;g<4;++g) w4g[g] = wih4[g*64 + lane];
  sV[lane] = 0.f;
  float c_state = 0.f;
  __syncthreads();

  for (int t = 0; t < T; ++t){
    u16 xr[4];
    #pragma unroll
    for (int g=0;g<4;++g) xr[g] = g_xp3[((u32)b*T + (u32)t)*256 + (u32)(g*64 + lane)];
    float a0=0.f, a1=0.f, a2=0.f, a3=0.f;
    #pragma unroll 4
    for (int k4 = 0; k4 < 16; ++k4){
      float4 v4 = *(const float4*)&sV[4*k4];
      #pragma unroll
      for (int m=0;m<4;++m){
        float4 w = *(const float4*)&sW[(4*k4+m)*256 + 4*lane];
        float vm = (&v4.x)[m];
        a0 = __builtin_fmaf(w.x, vm, a0);
        a1 = __builtin_fmaf(w.y, vm, a1);
        a2 = __builtin_fmaf(w.z, vm, a2);
        a3 = __builtin_fmaf(w.w, vm, a3);
      }
    }
    *(float4*)&sG[4*lane] = make_float4(a0,a1,a2,a3);
    __syncthreads();
    float gs[4];
    #pragma unroll
    for (int g=0;g<4;++g) gs[g] = sBs[g*64 + lane] + bf(xr[g]) + sG[g*64 + lane];
    float cg = sigm(gs[1])*c_state + sigm(gs[0])*tanh_(gs[2]);
    c_state = cg;
    float h = sigm(gs[3])*tanh_(cg);
    sV[lane] = h;
    float p[4];
    #pragma unroll
    for (int g=0;g<4;++g) p[g] = w4g[g]*h;
    #pragma unroll
    for (int off = 32; off; off >>= 1){
      #pragma unroll
      for (int g=0;g<4;++g) p[g] += __shfl_down(p[g], off);
    }
    if (lane == 0) g_xp4[(u32)b*T + t] = make_float4(p[0],p[1],p[2],p[3]);
    __syncthreads();
  }
}

// ============== Layer 4: H=1 scalar scan ==============
__global__ void k_l4(const float* __restrict__ whh, const float* __restrict__ bih,
                     const float* __restrict__ bhh, float* __restrict__ out){
  int b = blockIdx.x*64 + threadIdx.x;
  float wi=whh[0], wf=whh[1], wg=whh[2], wo=whh[3];
  float bi=bih[0]+bhh[0], bf_=bih[1]+bhh[1], bg=bih[2]+bhh[2], bo=bih[3]+bhh[3];
  float h=0.f, c=0.f;
  const float4* xp = &g_xp4[(u32)b*T];
  float4 nxt = xp[0];
  for (int t=0; t<T; ++t){
    float4 cur = nxt;
    if (t+1 < T) nxt = xp[t+1];
    float ig = sigm(cur.x + wi*h + bi);
    float fg = sigm(cur.y + wf*h + bf_);
    float gg = tanh_(cur.z + wg*h + bg);
    float og = sigm(cur.w + wo*h + bo);
    c = fg*c + ig*gg;
    h = og*tanh_(c);
  }
  out[b] = h;
}

extern "C" void kernel_launch(void* const* d_in, const int* in_sizes, int n_in,
                              void* d_out, int out_size, void* d_ws, size_t ws_size,
                              hipStream_t stream){
  (void)in_sizes; (void)n_in; (void)d_ws; (void)ws_size; (void)out_size;
  const float* x    = (const float*)d_in[0];
  const float* wih1 = (const float*)d_in[1];
  const float* whh1 = (const float*)d_in[2];
  const float* bih1 = (const float*)d_in[3];
  const float* bhh1 = (const float*)d_in[4];
  const float* wih2 = (const float*)d_in[5];
  const float* whh2 = (const float*)d_in[6];
  const float* bih2 = (const float*)d_in[7];
  const float* bhh2 = (const float*)d_in[8];
  const float* wih3 = (const float*)d_in[9];
  const float* whh3 = (const float*)d_in[10];
  const float* bih3 = (const float*)d_in[11];
  const float* bhh3 = (const float*)d_in[12];
  const float* wih4 = (const float*)d_in[13];
  const float* whh4 = (const float*)d_in[14];
  const float* bih4 = (const float*)d_in[15];
  const float* bhh4 = (const float*)d_in[16];

  hipLaunchKernelGGL(k_zero_flags, dim3(1), dim3(1024), 0, stream);
  hipLaunchKernelGGL(k_l1, dim3(240), dim3(320), 0, stream, x, wih1, whh1, bih1, bhh1);
  hipLaunchKernelGGL(k_l2, dim3(256), dim3(256), 0, stream, wih2, whh2, bih2, bhh2);
  hipLaunchKernelGGL(k_g3, dim3(8192), dim3(256), 0, stream, wih3);
  hipLaunchKernelGGL(k_l3, dim3(128), dim3(64), 0, stream, whh3, bih3, bhh3, wih4);
  hipLaunchKernelGGL(k_l4, dim3(2), dim3(64), 0, stream, whh4, bih4, bhh4, (float*)d_out);
}